// Round 6
// baseline (18955.310 us; speedup 1.0000x reference)
//
#include <hip/hip_runtime.h>
#include <cstddef>

// Problem constants (reference: B=8, S=512, E=128, H=512, ENC=128)
#define BB 8
#define SS 512
#define EE 128
#define HH 512
#define ENC 128

// ---------------------------------------------------------------------------
// Bit-exact emulation of XLA CPU's EmitTanh (elemental_ir_emitter, F32):
//   x_c = min(max(x, -9), 9); x2 = x_c*x_c
//   num = x_c * Horner(x2, {-2.76076847742355e-16, 2.00018790482477e-13,
//                           -8.60467152213735e-11, 5.12229709037114e-08,
//                            1.48572235717979e-05, 6.37261928875436e-04,
//                            4.89352455891786e-03})
//   den = Horner(x2, {1.19825839466702e-06, 1.18534705686654e-04,
//                     2.26843463243900e-03, 4.89352518554385e-03})
//   result = |x| < 0.0004 ? x : num/den
// All ops rn, NON-fused (XLA emits separate fmul/fadd; jaxlib CPU built
// without FMA contraction). __f*_rn intrinsics block compiler contraction.
// ---------------------------------------------------------------------------
__device__ __forceinline__ float xla_tanhf(float x) {
    const float cx = fminf(fmaxf(x, -9.0f), 9.0f);
    const float x2 = __fmul_rn(cx, cx);
    float p = -2.76076847742355e-16f;
    p = __fadd_rn(__fmul_rn(p, x2), 2.00018790482477e-13f);
    p = __fadd_rn(__fmul_rn(p, x2), -8.60467152213735e-11f);
    p = __fadd_rn(__fmul_rn(p, x2), 5.12229709037114e-08f);
    p = __fadd_rn(__fmul_rn(p, x2), 1.48572235717979e-05f);
    p = __fadd_rn(__fmul_rn(p, x2), 6.37261928875436e-04f);
    p = __fadd_rn(__fmul_rn(p, x2), 4.89352455891786e-03f);
    const float num = __fmul_rn(cx, p);
    float q = 1.19825839466702e-06f;
    q = __fadd_rn(__fmul_rn(q, x2), 1.18534705686654e-04f);
    q = __fadd_rn(__fmul_rn(q, x2), 2.26843463243900e-03f);
    q = __fadd_rn(__fmul_rn(q, x2), 4.89352518554385e-03f);
    const float r = __fdiv_rn(num, q);
    return (fabsf(x) < 0.0004f) ? x : r;
}

// Map a packed chunk-row m -> global action row:
//   b = m >> chsh (CH = chm1+1), global row = b*SS + i0 + (m & chm1)
__device__ __forceinline__ int arow_map(int m, int chm1, int chsh, int i0) {
    return ((m >> chsh) * SS) + i0 + (m & chm1);
}

// ---------------------------------------------------------------------------
// Naive row-GEMM (bitwise-ordered): C[m,n] = act(sum_k A[row(m),k]*B[n,k] + bias[n])
// Sequential ascending-k, NON-fused mul/add per element (Eigen-no-FMA /
// XLA-CPU dot semantics). grid.y = m (chunk-packed), grid.x*256+tid = n.
// ---------------------------------------------------------------------------
template <int ACT, int MAPROW>
__global__ __launch_bounds__(256) void ngemm(const float* __restrict__ A,
                                             const float* __restrict__ Bm,
                                             const float* __restrict__ bias,
                                             float* __restrict__ C,
                                             int N, int K,
                                             int chm1, int chsh, int i0) {
    __shared__ float Arow[512];  // K <= 512 always here
    const int m = blockIdx.y;
    const int n = blockIdx.x * 256 + threadIdx.x;
    const int ga = MAPROW ? arow_map(m, chm1, chsh, i0) : m;

    for (int k = threadIdx.x; k < K; k += 256) Arow[k] = A[(size_t)ga * K + k];
    __syncthreads();

    const float* Brow = Bm + (size_t)n * K;
    float sum = 0.f;
    for (int k = 0; k < K; ++k)
        sum = __fadd_rn(sum, __fmul_rn(Arow[k], Brow[k]));
    sum = __fadd_rn(sum, bias[n]);
    if (ACT) sum = xla_tanhf(sum);
    C[(size_t)m * N + n] = sum;
}

// ---------------------------------------------------------------------------
// Sequential attractor scan over one chunk of CH steps.
// One workgroup per batch, 128 threads; thread e sums d=0..127 ascending,
// non-fused mul/add.  et_i[e] = clip(sum_d et_{i-1}[d]*Wa[b,ii,d,e], -5, 5)
// Wa chunk-packed: row (b*CH + ii). et state (fp32) persists in ws.
// ---------------------------------------------------------------------------
__global__ __launch_bounds__(128) void scan_kernel(const float* __restrict__ Wa,
                                                   const float* __restrict__ e0,
                                                   float* __restrict__ et_state,
                                                   float* __restrict__ out,
                                                   int i0, int CH) {
    const int b = blockIdx.x;
    const int e = threadIdx.x;  // 0..127

    __shared__ float et[128];

    if (i0 != 0) et[e] = et_state[b * 128 + e];
    __syncthreads();

    for (int ii = 0; ii < CH; ++ii) {
        const int i = i0 + ii;
        if (i == 0) {  // step 0: et = e0, out[b,0,:] = e0
            const float v = e0[e];
            et[e] = v;
            out[(size_t)b * SS * ENC + e] = v;
            __syncthreads();
            continue;
        }
        const float* W = Wa + ((size_t)b * CH + ii) * (ENC * ENC);
        float sum = 0.f;
        for (int d = 0; d < 128; ++d)
            sum = __fadd_rn(sum, __fmul_rn(et[d], W[(size_t)d * ENC + e]));
        __syncthreads();  // all reads of et done before overwrite
        const float v = fminf(fmaxf(sum, -5.f), 5.f);  // jnp.clip
        et[e] = v;
        out[((size_t)b * SS + i) * ENC + e] = v;
        __syncthreads();
    }
    et_state[b * 128 + e] = et[e];
}

// ---------------------------------------------------------------------------
extern "C" void kernel_launch(void* const* d_in, const int* in_sizes, int n_in,
                              void* d_out, int out_size, void* d_ws, size_t ws_size,
                              hipStream_t stream) {
    const float* A  = (const float*)d_in[0];  // (B,S,E)   = (8,512,128) fp32
    const float* W1 = (const float*)d_in[1];  // (H,E)     = (512,128)  fp32
    const float* b1 = (const float*)d_in[2];  // (H,)      fp32
    const float* W2 = (const float*)d_in[3];  // (ENC*ENC,H) = (16384,512) fp32
    const float* b2 = (const float*)d_in[4];  // (ENC*ENC,) fp32
    const float* e0 = (const float*)d_in[5];  // (1,ENC)   fp32
    float* out = (float*)d_out;               // (B,S,ENC) fp32

    // Pick the largest chunk CH (steps) whose fp32 workspace fits ws_size.
    // ws layout: [et_state 4KB][hidden_c Mc*512 f32][Wa_c Mc*16384 f32], Mc=8*CH
    int CH = 16;  // minimum; needs ~8.7 MB
    for (int c = 512; c >= 16; c >>= 1) {
        const size_t Mc = (size_t)BB * c;
        const size_t need = 4096 + Mc * HH * sizeof(float) +
                            Mc * (size_t)(ENC * ENC) * sizeof(float);
        if (need <= ws_size) { CH = c; break; }
    }
    const int Mc = BB * CH;
    int chsh = 0;
    while ((1 << chsh) < CH) ++chsh;
    const int chm1 = CH - 1;

    float* et_state = (float*)d_ws;
    float* hidden   = (float*)((char*)d_ws + 4096);
    float* Wa       = hidden + (size_t)Mc * HH;

    for (int i0 = 0; i0 < SS; i0 += CH) {
        // GEMM1: hidden_c = tanh(A[chunk rows] @ W1^T + b1)  [Mc x 512, K=128]
        dim3 g1(HH / 256, Mc);  // (2, Mc)
        ngemm<1, 1><<<g1, 256, 0, stream>>>(A, W1, b1, hidden, HH, EE,
                                            chm1, chsh, i0);
        // GEMM2: Wa_c = hidden_c @ W2^T + b2   [Mc x 16384, K=512]
        dim3 g2((ENC * ENC) / 256, Mc);  // (64, Mc)
        ngemm<0, 0><<<g2, 256, 0, stream>>>(hidden, W2, b2, Wa, ENC * ENC, HH,
                                            0, 0, 0);
        // scan this chunk (one workgroup per batch; fp32 state in ws)
        scan_kernel<<<BB, 128, 0, stream>>>(Wa, e0, et_state, out, i0, CH);
    }
}

// Round 7
// 2379.405 us; speedup vs baseline: 7.9664x; 7.9664x over previous
//
#include <hip/hip_runtime.h>
#include <cstddef>

// Problem constants (reference: B=8, S=512, E=128, H=512, ENC=128)
#define BB 8
#define SS 512
#define EE 128
#define HH 512
#define ENC 128

// ---------------------------------------------------------------------------
// Bit-exact emulation of XLA CPU's EmitTanh (verified bitwise in round 6).
// All ops rn, NON-fused. __f*_rn intrinsics block compiler contraction.
// ---------------------------------------------------------------------------
__device__ __forceinline__ float xla_tanhf(float x) {
    const float cx = fminf(fmaxf(x, -9.0f), 9.0f);
    const float x2 = __fmul_rn(cx, cx);
    float p = -2.76076847742355e-16f;
    p = __fadd_rn(__fmul_rn(p, x2), 2.00018790482477e-13f);
    p = __fadd_rn(__fmul_rn(p, x2), -8.60467152213735e-11f);
    p = __fadd_rn(__fmul_rn(p, x2), 5.12229709037114e-08f);
    p = __fadd_rn(__fmul_rn(p, x2), 1.48572235717979e-05f);
    p = __fadd_rn(__fmul_rn(p, x2), 6.37261928875436e-04f);
    p = __fadd_rn(__fmul_rn(p, x2), 4.89352455891786e-03f);
    const float num = __fmul_rn(cx, p);
    float q = 1.19825839466702e-06f;
    q = __fadd_rn(__fmul_rn(q, x2), 1.18534705686654e-04f);
    q = __fadd_rn(__fmul_rn(q, x2), 2.26843463243900e-03f);
    q = __fadd_rn(__fmul_rn(q, x2), 4.89352518554385e-03f);
    const float r = __fdiv_rn(num, q);
    return (fabsf(x) < 0.0004f) ? x : r;
}

// Map a packed chunk-row m -> global action row:
//   b = m >> chsh (CH = chm1+1), global row = b*SS + i0 + (m & chm1)
__device__ __forceinline__ int arow_map(int m, int chm1, int chsh, int i0) {
    return ((m >> chsh) * SS) + i0 + (m & chm1);
}

// ---------------------------------------------------------------------------
// Tiled GEMM, bitwise-preserving XLA-CPU dot semantics:
//   C[m,n] = act( seq_{k=0..K-1} add(mul(A[row(m),k], B[n,k])) + bias[n] )
// Each output element has ONE fp32 accumulator; k0 tiles ascend, inner k
// ascends => identical rounding chain to the naive kernel (verified r6).
// Tiles BM=BN=128, BK=16; 256 threads; 8x8 outputs/thread; LDS-staged.
// MAPROW=1: A rows chunk-packed via arow_map. Dims are tile multiples.
// ---------------------------------------------------------------------------
template <int ACT, int MAPROW>
__global__ __launch_bounds__(256) void gemm_nt(const float* __restrict__ A,
                                               const float* __restrict__ Bm,
                                               const float* __restrict__ bias,
                                               float* __restrict__ C,
                                               int N, int K,
                                               int chm1, int chsh, int i0) {
    __shared__ float As[16][128];
    __shared__ float Bs[16][128];

    const int tid = threadIdx.x;
    const int tx = tid & 15;   // n-direction (8 cols each)
    const int ty = tid >> 4;   // m-direction (8 rows each)
    const int n0 = blockIdx.x * 128;
    const int m0 = blockIdx.y * 128;

    const int lr = tid >> 2;          // 0..63 (row within tile)
    const int lc = (tid & 3) << 2;    // 0,4,8,12 (col within K-tile)

    const int ga0 = MAPROW ? arow_map(m0 + lr, chm1, chsh, i0) : (m0 + lr);
    const int ga1 = MAPROW ? arow_map(m0 + lr + 64, chm1, chsh, i0) : (m0 + lr + 64);

    float acc[8][8];
#pragma unroll
    for (int i = 0; i < 8; ++i)
#pragma unroll
        for (int j = 0; j < 8; ++j) acc[i][j] = 0.f;

    for (int k0 = 0; k0 < K; k0 += 16) {
        const float4 a0 = *(const float4*)(A + (size_t)ga0 * K + (k0 + lc));
        const float4 a1 = *(const float4*)(A + (size_t)ga1 * K + (k0 + lc));
        const float4 b0 = *(const float4*)(Bm + (size_t)(n0 + lr) * K + (k0 + lc));
        const float4 b1 = *(const float4*)(Bm + (size_t)(n0 + lr + 64) * K + (k0 + lc));

        __syncthreads();  // previous iteration's compute done before overwrite

        As[lc + 0][lr] = a0.x; As[lc + 1][lr] = a0.y;
        As[lc + 2][lr] = a0.z; As[lc + 3][lr] = a0.w;
        As[lc + 0][lr + 64] = a1.x; As[lc + 1][lr + 64] = a1.y;
        As[lc + 2][lr + 64] = a1.z; As[lc + 3][lr + 64] = a1.w;
        Bs[lc + 0][lr] = b0.x; Bs[lc + 1][lr] = b0.y;
        Bs[lc + 2][lr] = b0.z; Bs[lc + 3][lr] = b0.w;
        Bs[lc + 0][lr + 64] = b1.x; Bs[lc + 1][lr + 64] = b1.y;
        Bs[lc + 2][lr + 64] = b1.z; Bs[lc + 3][lr + 64] = b1.w;

        __syncthreads();

#pragma unroll
        for (int k = 0; k < 16; ++k) {   // ascending k within tile
            const float4 av0 = *(const float4*)&As[k][ty * 8];
            const float4 av1 = *(const float4*)&As[k][ty * 8 + 4];
            const float4 bv0 = *(const float4*)&Bs[k][tx * 8];
            const float4 bv1 = *(const float4*)&Bs[k][tx * 8 + 4];
            const float a[8] = {av0.x, av0.y, av0.z, av0.w, av1.x, av1.y, av1.z, av1.w};
            const float b[8] = {bv0.x, bv0.y, bv0.z, bv0.w, bv1.x, bv1.y, bv1.z, bv1.w};
#pragma unroll
            for (int i = 0; i < 8; ++i)
#pragma unroll
                for (int j = 0; j < 8; ++j)
                    acc[i][j] = __fadd_rn(acc[i][j], __fmul_rn(a[i], b[j]));
        }
    }

    // epilogue: + bias (after full k-chain), optional XLA tanh, float4 store
#pragma unroll
    for (int i = 0; i < 8; ++i) {
        const int m = m0 + ty * 8 + i;
        float v[8];
#pragma unroll
        for (int j = 0; j < 8; ++j) {
            const int n = n0 + tx * 8 + j;
            v[j] = __fadd_rn(acc[i][j], bias[n]);
            if (ACT) v[j] = xla_tanhf(v[j]);
        }
        float4* dst = (float4*)(C + (size_t)m * N + (n0 + tx * 8));
        dst[0] = make_float4(v[0], v[1], v[2], v[3]);
        dst[1] = make_float4(v[4], v[5], v[6], v[7]);
    }
}

// ---------------------------------------------------------------------------
// Sequential attractor scan over one chunk of CH steps (bitwise-verified r6).
// One workgroup per batch, 128 threads; thread e sums d=0..127 ascending,
// non-fused mul/add.  et_i[e] = clip(sum_d et_{i-1}[d]*Wa[b,ii,d,e], -5, 5)
// ---------------------------------------------------------------------------
__global__ __launch_bounds__(128) void scan_kernel(const float* __restrict__ Wa,
                                                   const float* __restrict__ e0,
                                                   float* __restrict__ et_state,
                                                   float* __restrict__ out,
                                                   int i0, int CH) {
    const int b = blockIdx.x;
    const int e = threadIdx.x;  // 0..127

    __shared__ float et[128];

    if (i0 != 0) et[e] = et_state[b * 128 + e];
    __syncthreads();

    for (int ii = 0; ii < CH; ++ii) {
        const int i = i0 + ii;
        if (i == 0) {  // step 0: et = e0, out[b,0,:] = e0
            const float v = e0[e];
            et[e] = v;
            out[(size_t)b * SS * ENC + e] = v;
            __syncthreads();
            continue;
        }
        const float* W = Wa + ((size_t)b * CH + ii) * (ENC * ENC);
        float sum = 0.f;
        for (int d = 0; d < 128; ++d)
            sum = __fadd_rn(sum, __fmul_rn(et[d], W[(size_t)d * ENC + e]));
        __syncthreads();  // all reads of et done before overwrite
        const float v = fminf(fmaxf(sum, -5.f), 5.f);  // jnp.clip
        et[e] = v;
        out[((size_t)b * SS + i) * ENC + e] = v;
        __syncthreads();
    }
    et_state[b * 128 + e] = et[e];
}

// ---------------------------------------------------------------------------
extern "C" void kernel_launch(void* const* d_in, const int* in_sizes, int n_in,
                              void* d_out, int out_size, void* d_ws, size_t ws_size,
                              hipStream_t stream) {
    const float* A  = (const float*)d_in[0];  // (B,S,E)   = (8,512,128) fp32
    const float* W1 = (const float*)d_in[1];  // (H,E)     = (512,128)  fp32
    const float* b1 = (const float*)d_in[2];  // (H,)      fp32
    const float* W2 = (const float*)d_in[3];  // (ENC*ENC,H) = (16384,512) fp32
    const float* b2 = (const float*)d_in[4];  // (ENC*ENC,) fp32
    const float* e0 = (const float*)d_in[5];  // (1,ENC)   fp32
    float* out = (float*)d_out;               // (B,S,ENC) fp32

    // Pick the largest chunk CH (steps) whose fp32 workspace fits ws_size.
    // ws layout: [et_state 4KB][hidden_c Mc*512 f32][Wa_c Mc*16384 f32], Mc=8*CH
    int CH = 16;  // minimum (Mc=128, one M-tile); needs ~8.7 MB
    for (int c = 512; c >= 16; c >>= 1) {
        const size_t Mc = (size_t)BB * c;
        const size_t need = 4096 + Mc * HH * sizeof(float) +
                            Mc * (size_t)(ENC * ENC) * sizeof(float);
        if (need <= ws_size) { CH = c; break; }
    }
    const int Mc = BB * CH;
    int chsh = 0;
    while ((1 << chsh) < CH) ++chsh;
    const int chm1 = CH - 1;

    float* et_state = (float*)d_ws;
    float* hidden   = (float*)((char*)d_ws + 4096);
    float* Wa       = hidden + (size_t)Mc * HH;

    for (int i0 = 0; i0 < SS; i0 += CH) {
        // GEMM1: hidden_c = tanh(A[chunk rows] @ W1^T + b1)  [Mc x 512, K=128]
        dim3 g1(HH / 128, Mc / 128);
        gemm_nt<1, 1><<<g1, 256, 0, stream>>>(A, W1, b1, hidden, HH, EE,
                                              chm1, chsh, i0);
        // GEMM2: Wa_c = hidden_c @ W2^T + b2   [Mc x 16384, K=512]
        dim3 g2((ENC * ENC) / 128, Mc / 128);
        gemm_nt<0, 0><<<g2, 256, 0, stream>>>(hidden, W2, b2, Wa, ENC * ENC, HH,
                                              0, 0, 0);
        // scan this chunk (one workgroup per batch; fp32 state in ws)
        scan_kernel<<<BB, 128, 0, stream>>>(Wa, e0, et_state, out, i0, CH);
    }
}